// Round 7
// baseline (402.221 us; speedup 1.0000x reference)
//
#include <hip/hip_runtime.h>
#include <cstdint>

typedef __bf16 bf16_t;
typedef __bf16 bf16x4 __attribute__((ext_vector_type(4)));
typedef __bf16 bf16x8 __attribute__((ext_vector_type(8)));
typedef float f32x4 __attribute__((ext_vector_type(4)));

#define B_ 4
#define S_ 1024
#define D_ 1024
#define HID_ 4096
#define MEG (1u << 20)

// ---------------- workspace layout (bytes) ----------------
static const size_t OFF_WBF  = 0;                 // 12M bf16 (Wq,Wk,Wv,Wo,W1,W2)
static const size_t OFF_BQKV = 25165824;          // 3072 f32
static const size_t OFF_MOD  = 25178112;          // 4*6144 f32
static const size_t OFF_H    = 25276416;          // 4096*1024 bf16
static const size_t OFF_QKV  = 33665024;          // 4096*3072 bf16
static const size_t OFF_VT   = 58830848;          // 4*16*64*1024 bf16
static const size_t OFF_ATTN = 67219456;          // 4096*1024 bf16
static const size_t OFF_X1   = 75608064;          // 4096*1024 f32
static const size_t OFF_PART = 92385280;          // 2 * 4096*1024 f32 (split-K partials)
static const size_t OFF_MLPH = 159494144;         // 4096*4096 bf16 = 32MB

// ---------------- async global->LDS (16B/lane) ----------------
__device__ __forceinline__ void async_copy16(const bf16_t* g, bf16_t* l) {
  __builtin_amdgcn_global_load_lds(
      (__attribute__((address_space(1))) void*)(g),
      (__attribute__((address_space(3))) void*)(l), 16, 0, 0);
}

// ---------------- weight convert + bias pack ----------------
__global__ __launch_bounds__(256) void convert_pack(
    const float* __restrict__ Wq, const float* __restrict__ Wk,
    const float* __restrict__ Wv, const float* __restrict__ Wo,
    const float* __restrict__ W1, const float* __restrict__ W2,
    const float* __restrict__ bq, const float* __restrict__ bk,
    const float* __restrict__ bv, bf16_t* __restrict__ wbf,
    float* __restrict__ bqkv) {
  const int y = blockIdx.y;
  if (y == 6) {
    int i = blockIdx.x * 256 + threadIdx.x;
    if (i < 3072)
      bqkv[i] = i < 1024 ? bq[i] : (i < 2048 ? bk[i - 1024] : bv[i - 2048]);
    return;
  }
  const float* src; bf16_t* dst; int n;
  switch (y) {
    case 0: src = Wq; dst = wbf;           n = MEG;     break;
    case 1: src = Wk; dst = wbf + MEG;     n = MEG;     break;
    case 2: src = Wv; dst = wbf + 2*MEG;   n = MEG;     break;
    case 3: src = Wo; dst = wbf + 3*MEG;   n = MEG;     break;
    case 4: src = W1; dst = wbf + 4*MEG;   n = 4*MEG;   break;
    default: src = W2; dst = wbf + 8*MEG;  n = 4*MEG;   break;
  }
  int idx = (blockIdx.x * 256 + threadIdx.x) * 4;
  if (idx < n) {
    float4 v = *(const float4*)(src + idx);
    bf16x4 pk;
    pk.x = (__bf16)v.x; pk.y = (__bf16)v.y; pk.z = (__bf16)v.z; pk.w = (__bf16)v.w;
    *(bf16x4*)(dst + idx) = pk;
  }
}

// ---------------- adaLN: one wave per output o, all 4 batches ----------------
__global__ __launch_bounds__(256) void ada_mod(
    const float* __restrict__ cond, const float* __restrict__ Wada,
    const float* __restrict__ bada, float* __restrict__ mod) {
  const int wave = threadIdx.x >> 6, lane = threadIdx.x & 63;
  const int o = blockIdx.x * 4 + wave;      // 0..6143
  const float* wr = Wada + (size_t)o * D_;
  float a0 = 0.f, a1 = 0.f, a2 = 0.f, a3 = 0.f;
#pragma unroll
  for (int l = 0; l < 16; l++) {
    int i = l * 64 + lane;
    float w = wr[i];
    float c0 = cond[i], c1 = cond[1024 + i], c2 = cond[2048 + i], c3 = cond[3072 + i];
    a0 += w * (c0 / (1.0f + __expf(-c0)));
    a1 += w * (c1 / (1.0f + __expf(-c1)));
    a2 += w * (c2 / (1.0f + __expf(-c2)));
    a3 += w * (c3 / (1.0f + __expf(-c3)));
  }
#pragma unroll
  for (int offs = 32; offs; offs >>= 1) {
    a0 += __shfl_xor(a0, offs);
    a1 += __shfl_xor(a1, offs);
    a2 += __shfl_xor(a2, offs);
    a3 += __shfl_xor(a3, offs);
  }
  if (lane == 0) {
    float bb = bada[o];
    mod[o]          = a0 + bb;
    mod[6144 + o]   = a1 + bb;
    mod[12288 + o]  = a2 + bb;
    mod[18432 + o]  = a3 + bb;
  }
}

// ---------------- LayerNorm + modulate -> bf16 ----------------
__global__ __launch_bounds__(256) void ln_modulate(
    const float* __restrict__ X, const float* __restrict__ mod,
    bf16_t* __restrict__ H, int goff) {
  const int row = blockIdx.x;
  const int b = row >> 10;
  const int t = threadIdx.x;
  const float* xr = X + (size_t)row * D_;
  float4 xv = *(const float4*)(xr + t * 4);
  float s = xv.x + xv.y + xv.z + xv.w;
  float q = xv.x*xv.x + xv.y*xv.y + xv.z*xv.z + xv.w*xv.w;
  const int wave = t >> 6, lane = t & 63;
#pragma unroll
  for (int offs = 32; offs; offs >>= 1) {
    s += __shfl_down(s, offs);
    q += __shfl_down(q, offs);
  }
  __shared__ float sb[4][2];
  if (lane == 0) { sb[wave][0] = s; sb[wave][1] = q; }
  __syncthreads();
  float st = sb[0][0] + sb[1][0] + sb[2][0] + sb[3][0];
  float qt = sb[0][1] + sb[1][1] + sb[2][1] + sb[3][1];
  float mu = st * (1.0f / D_);
  float var = qt * (1.0f / D_) - mu * mu;
  float rstd = rsqrtf(var + 1e-6f);
  const float* mb = mod + (size_t)b * 6144 + goff;
  const int c = t * 4;
  float4 gm = *(const float4*)(mb + c);
  float4 bt = *(const float4*)(mb + 1024 + c);
  bf16x4 pk;
  pk.x = (__bf16)((xv.x - mu) * rstd * (1.0f + bt.x) + gm.x);
  pk.y = (__bf16)((xv.y - mu) * rstd * (1.0f + bt.y) + gm.y);
  pk.z = (__bf16)((xv.z - mu) * rstd * (1.0f + bt.z) + gm.z);
  pk.w = (__bf16)((xv.w - mu) * rstd * (1.0f + bt.w) + gm.w);
  *(bf16x4*)(H + (size_t)row * D_ + c) = pk;
}

// ---------------- V transpose: vT[b,h,d,s] <- qkv[b,s, 2048+h*64+d] ----------------
__global__ __launch_bounds__(256) void transpose_v(
    const bf16_t* __restrict__ qkv, bf16_t* __restrict__ vT) {
  __shared__ bf16_t tile[64][65];
  const int bh = blockIdx.y;
  const int b = bh >> 4, hh = bh & 15;
  const int s0 = blockIdx.x * 64;
  const int t = threadIdx.x;
  const int tx = t & 63, ty = t >> 6;
  const bf16_t* src = qkv + (size_t)b * S_ * 3072 + 2048 + hh * 64;
  for (int r = ty; r < 64; r += 4)
    tile[r][tx] = src[(size_t)(s0 + r) * 3072 + tx];
  __syncthreads();
  bf16_t* dst = vT + (size_t)bh * 64 * 1024;
  for (int r = ty; r < 64; r += 4)
    dst[(size_t)r * 1024 + s0 + tx] = tile[tx][r];
}

// ---------------- flash attention (S^T formulation) ----------------
// Per K-tile: accT = K Q^T (C-layout: row=k, col=q) -> lane-wise softmax for
// q=lm (cross-quad shfl 16/32) -> contiguous b64 P store (A-layout) -> O += P V.
__global__ __launch_bounds__(256) void flash_attn(
    const bf16_t* __restrict__ qkv, const bf16_t* __restrict__ vT,
    bf16_t* __restrict__ attn) {
  __shared__ __align__(16) bf16_t Qs[64 * 64];
  __shared__ __align__(16) bf16_t Ks[128 * 64];
  __shared__ __align__(16) bf16_t Vs[64 * 128];
  __shared__ __align__(16) bf16_t Ps[4 * 16 * 136];

  const int t = threadIdx.x;
  const int wave = t >> 6, lane = t & 63;
  const int lm = lane & 15, quad = lane >> 4;
  const int bh = blockIdx.y;
  const int b = bh >> 4, hh = bh & 15;
  const int s0 = blockIdx.x * 64;

  const bf16_t* qbase = qkv + (size_t)b * S_ * 3072 + hh * 64;
  const bf16_t* kbase = qbase + 1024;
  const bf16_t* vbase = vT + (size_t)bh * (64 * 1024);

#pragma unroll
  for (int j = 0; j < 2; j++) {
    int slot = j * 256 + t;
    int row = slot >> 3;
    int cg = (slot & 7) ^ (row & 7);
    async_copy16(qbase + (size_t)(s0 + row) * 3072 + cg * 8, &Qs[slot * 8]);
  }
  __syncthreads();

  // Q B-frags (loop-invariant): B[n=q=wave*16+lm][d=ks*32+quad*8+j]
  bf16x8 bq[2];
  {
    int rq = wave * 16 + lm;
#pragma unroll
    for (int ks = 0; ks < 2; ks++) {
      int cq = (ks * 4 + quad) ^ (rq & 7);
      bq[ks] = *(const bf16x8*)&Qs[rq * 64 + cq * 8];
    }
  }

  f32x4 accO[4] = {};
  float m2 = -1e30f, lsm = 0.f;           // softmax state for q = wave*16+lm
  const float sc = 0.1803368801f;         // 0.125 * log2(e)

  bf16_t* Pw = &Ps[wave * 16 * 136];

  for (int k0 = 0; k0 < S_; k0 += 128) {
    __syncthreads();
#pragma unroll
    for (int j = 0; j < 4; j++) {
      int slot = j * 256 + t;
      int row = slot >> 3;
      int cg = (slot & 7) ^ (row & 7);
      async_copy16(kbase + (size_t)(k0 + row) * 3072 + cg * 8, &Ks[slot * 8]);
    }
#pragma unroll
    for (int j = 0; j < 4; j++) {
      int slot = j * 256 + t;
      int row = slot >> 4;
      int cp = slot & 15;
      int cg = (cp & 8) | ((cp & 7) ^ (row & 7));
      async_copy16(vbase + (size_t)row * 1024 + k0 + cg * 8, &Vs[slot * 8]);
    }
    __syncthreads();

    // accT[ni][r] = S^T[k = ni*16+quad*4+r][q = wave*16+lm]
    f32x4 accT[8] = {};
#pragma unroll
    for (int ks = 0; ks < 2; ks++) {
#pragma unroll
      for (int ni = 0; ni < 8; ni++) {
        int rk = ni * 16 + lm;
        int ck = (ks * 4 + quad) ^ (rk & 7);
        bf16x8 ak = *(const bf16x8*)&Ks[rk * 64 + ck * 8];
        accT[ni] = __builtin_amdgcn_mfma_f32_16x16x32_bf16(ak, bq[ks], accT[ni], 0, 0, 0);
      }
    }

    // lane-wise online softmax (32 values of one q-row per lane)
    f32x4 m4 = accT[0];
#pragma unroll
    for (int ni = 1; ni < 8; ni++) {
      m4[0] = fmaxf(m4[0], accT[ni][0]); m4[1] = fmaxf(m4[1], accT[ni][1]);
      m4[2] = fmaxf(m4[2], accT[ni][2]); m4[3] = fmaxf(m4[3], accT[ni][3]);
    }
    float mx = fmaxf(fmaxf(m4[0], m4[1]), fmaxf(m4[2], m4[3]));
    mx = fmaxf(mx, __shfl_xor(mx, 16));
    mx = fmaxf(mx, __shfl_xor(mx, 32));
    float m2new = fmaxf(m2, mx * sc);
    float alpha = exp2f(m2 - m2new);
    m2 = m2new;
    float psum = 0.f;
#pragma unroll
    for (int ni = 0; ni < 8; ni++) {
#pragma unroll
      for (int r = 0; r < 4; r++) {
        float p = exp2f(accT[ni][r] * sc - m2new);
        accT[ni][r] = p;
        psum += p;
      }
    }
    psum += __shfl_xor(psum, 16);
    psum += __shfl_xor(psum, 32);
    lsm = lsm * alpha + psum;

    // rescale accO (rows q = wave*16 + quad*4 + r)
    float al4[4];
#pragma unroll
    for (int r = 0; r < 4; r++) al4[r] = __shfl(alpha, quad * 20 + r);
#pragma unroll
    for (int di = 0; di < 4; di++)
#pragma unroll
      for (int r = 0; r < 4; r++) accO[di][r] *= al4[r];

    // P store: A-layout P[q=lm][k], contiguous bf16x4 per (lane, ni)
#pragma unroll
    for (int ni = 0; ni < 8; ni++) {
      bf16x4 pk4;
      pk4.x = (__bf16)accT[ni][0]; pk4.y = (__bf16)accT[ni][1];
      pk4.z = (__bf16)accT[ni][2]; pk4.w = (__bf16)accT[ni][3];
      *(bf16x4*)&Pw[lm * 136 + ni * 16 + quad * 4] = pk4;
    }

    // O += P V
#pragma unroll
    for (int ks2 = 0; ks2 < 4; ks2++) {
      bf16x8 ap = *(const bf16x8*)&Pw[lm * 136 + ks2 * 32 + quad * 8];
#pragma unroll
      for (int di = 0; di < 4; di++) {
        int rv = di * 16 + lm;
        int g = ks2 * 4 + quad;
        int cp = (g & 8) | ((g & 7) ^ (rv & 7));
        bf16x8 bv = *(const bf16x8*)&Vs[rv * 128 + cp * 8];
        accO[di] = __builtin_amdgcn_mfma_f32_16x16x32_bf16(ap, bv, accO[di], 0, 0, 0);
      }
    }
  }

  // epilogue: O/l -> wave-private LDS -> coalesced 16B stores
  float linv = 1.0f / lsm;
  float inv4[4];
#pragma unroll
  for (int r = 0; r < 4; r++) inv4[r] = __shfl(linv, quad * 20 + r);
#pragma unroll
  for (int r = 0; r < 4; r++) {
    int row = quad * 4 + r;
#pragma unroll
    for (int di = 0; di < 4; di++) {
      int col = di * 16 + lm;
      int cph = (col >> 3) ^ (row & 7);
      Pw[row * 64 + cph * 8 + (col & 7)] = (__bf16)(accO[di][r] * inv4[r]);
    }
  }
  bf16_t* abase = attn + (size_t)b * S_ * 1024 +
                  (size_t)(s0 + wave * 16) * 1024 + hh * 64;
#pragma unroll
  for (int it = 0; it < 2; it++) {
    int slot = it * 64 + lane;
    int row = slot >> 3;
    int cg = slot & 7;
    int cph = cg ^ (row & 7);
    bf16x8 val = *(const bf16x8*)&Pw[row * 64 + cph * 8];
    *(bf16x8*)(abase + (size_t)row * 1024 + cg * 8) = val;
  }
}

// ---------------- generic C = A * B^T GEMM, triple-buffered pipeline ----------------
// BK=32, 3 LDS buffers, loads stay 2 tiles ahead, s_waitcnt vmcnt(4) (never 0
// until the last tile). XCD-aware block swizzle (requires gridDim.y == 32).
// M,N multiples of 128; K multiple of 32.
// EPI: 0 = (+bias) -> bf16 ; 1 = *scale -> f32 ; 3 = gelu_tanh(acc+bias) -> bf16
template <int EPI>
__global__ __launch_bounds__(256) void gemm_bt(
    const bf16_t* __restrict__ A, int lda, long long sAz,
    const bf16_t* __restrict__ B, int ldb, long long sBz,
    void* __restrict__ Cv, int ldc, long long sCz,
    int M, int N, int K,
    const float* __restrict__ bias,
    float scale) {
  __shared__ __align__(16) bf16_t As[3][128 * 32];
  __shared__ __align__(16) bf16_t Bs[3][128 * 32];

  const int z = blockIdx.z;
  A += (size_t)z * sAz;
  B += (size_t)z * sBz;

  int d = blockIdx.x + gridDim.x * blockIdx.y;
  int xcd = d & 7, sId = d >> 3;
  int qq = sId & 31, panel = sId >> 5;
  const int bx = panel * 8 + (qq >> 2);
  const int by = xcd * 4 + (qq & 3);

  const int t = threadIdx.x;
  const int wave = t >> 6;
  const int lane = t & 63;
  const int lm = lane & 15;
  const int quad = lane >> 4;
  const int wr = wave >> 1;
  const int wc = wave & 1;

  const int m0 = by * 128;
  const int n0 = bx * 128;

  f32x4 acc[4][4] = {};

  // staging: thread t covers rows {t>>2, 64+(t>>2)}, LDS slot t&3 holds
  // global chunk (t&3) ^ ((srow>>1)&3)
  const int srow = t >> 2;
  const int gch = (t & 3) ^ ((srow >> 1) & 3);
  const int lds_off = t * 8;
  const bf16_t* Ap0 = A + (size_t)(m0 + srow) * lda + gch * 8;
  const bf16_t* Ap1 = A + (size_t)(m0 + 64 + srow) * lda + gch * 8;
  const bf16_t* Bp0 = B + (size_t)(n0 + srow) * ldb + gch * 8;
  const bf16_t* Bp1 = B + (size_t)(n0 + 64 + srow) * ldb + gch * 8;

  // reader slot offset (loop-invariant)
  const int sOff = (quad ^ ((lm >> 1) & 3)) * 8;

  const int niter = K >> 5;
  // prologue: tiles 0,1 -> buffers 0,1
  async_copy16(Ap0, &As[0][lds_off]);
  async_copy16(Ap1, &As[0][2048 + lds_off]);
  async_copy16(Bp0, &Bs[0][lds_off]);
  async_copy16(Bp1, &Bs[0][2048 + lds_off]);
  if (niter > 1) {
    async_copy16(Ap0 + 32, &As[1][lds_off]);
    async_copy16(Ap1 + 32, &As[1][2048 + lds_off]);
    async_copy16(Bp0 + 32, &Bs[1][lds_off]);
    async_copy16(Bp1 + 32, &Bs[1][2048 + lds_off]);
  }

  int rbuf = 0, wbuf = 2;
  for (int it = 0; it < niter; ++it) {
    if (it + 1 < niter)
      asm volatile("s_waitcnt vmcnt(4)\n\ts_barrier" ::: "memory");
    else
      asm volatile("s_waitcnt vmcnt(0)\n\ts_barrier" ::: "memory");
    if (it + 2 < niter) {
      const int ko = (it + 2) << 5;
      async_copy16(Ap0 + ko, &As[wbuf][lds_off]);
      async_copy16(Ap1 + ko, &As[wbuf][2048 + lds_off]);
      async_copy16(Bp0 + ko, &Bs[wbuf][lds_off]);
      async_copy16(Bp1 + ko, &Bs[wbuf][2048 + lds_off]);
    }
    wbuf = (wbuf == 2) ? 0 : wbuf + 1;
    bf16x8 af[4], bfr[4];
#pragma unroll
    for (int i = 0; i < 4; i++) {
      af[i] = *(const bf16x8*)&As[rbuf][(wr * 64 + i * 16 + lm) * 32 + sOff];
      bfr[i] = *(const bf16x8*)&Bs[rbuf][(wc * 64 + i * 16 + lm) * 32 + sOff];
    }
    rbuf = (rbuf == 2) ? 0 : rbuf + 1;
#pragma unroll
    for (int mi = 0; mi < 4; mi++)
#pragma unroll
      for (int ni = 0; ni < 4; ni++)
        acc[mi][ni] = __builtin_amdgcn_mfma_f32_16x16x32_bf16(
            af[mi], bfr[ni], acc[mi][ni], 0, 0, 0);
  }

  const size_t cz = (size_t)z * sCz;
#pragma unroll
  for (int mi = 0; mi < 4; mi++) {
#pragma unroll
    for (int ni = 0; ni < 4; ni++) {
#pragma unroll
      for (int r = 0; r < 4; r++) {
        int row = m0 + wr * 64 + mi * 16 + quad * 4 + r;
        int col = n0 + wc * 64 + ni * 16 + lm;
        float v = acc[mi][ni][r];
        size_t idx = cz + (size_t)row * ldc + col;
        if (EPI == 1) {
          ((float*)Cv)[idx] = v * scale;
        } else if (EPI == 0) {
          if (bias) v += bias[col];
          ((bf16_t*)Cv)[idx] = (__bf16)v;
        } else if (EPI == 3) {
          v += bias[col];
          float u = 1.5957691216f * (v + 0.044715f * v * v * v);
          float g = v / (1.0f + __expf(-u));
          ((bf16_t*)Cv)[idx] = (__bf16)g;
        }
      }
    }
  }
}

// ---------------- Wo split-K reduce + residual + LN2 + modulate ----------------
__global__ __launch_bounds__(256) void reduce_ln(
    const float* __restrict__ part, const float* __restrict__ x,
    const float* __restrict__ bo, const float* __restrict__ mod,
    float* __restrict__ x1, bf16_t* __restrict__ h) {
  const int row = blockIdx.x;
  const int b = row >> 10;
  const int t = threadIdx.x;
  const int c = t * 4;
  const size_t idx = (size_t)row * 1024 + c;
  float4 p0 = *(const float4*)(part + idx);
  float4 p1 = *(const float4*)(part + 4194304 + idx);
  float4 bb = *(const float4*)(bo + c);
  float4 al = *(const float4*)(mod + (size_t)b * 6144 + 2048 + c);
  float4 xs = *(const float4*)(x + idx);
  float4 xv;
  xv.x = xs.x + al.x * (p0.x + p1.x + bb.x);
  xv.y = xs.y + al.y * (p0.y + p1.y + bb.y);
  xv.z = xs.z + al.z * (p0.z + p1.z + bb.z);
  xv.w = xs.w + al.w * (p0.w + p1.w + bb.w);
  *(float4*)(x1 + idx) = xv;

  float s = xv.x + xv.y + xv.z + xv.w;
  float q = xv.x*xv.x + xv.y*xv.y + xv.z*xv.z + xv.w*xv.w;
  const int wave = t >> 6, lane = t & 63;
#pragma unroll
  for (int offs = 32; offs; offs >>= 1) {
    s += __shfl_down(s, offs);
    q += __shfl_down(q, offs);
  }
  __shared__ float sb[4][2];
  if (lane == 0) { sb[wave][0] = s; sb[wave][1] = q; }
  __syncthreads();
  float st = sb[0][0] + sb[1][0] + sb[2][0] + sb[3][0];
  float qt = sb[0][1] + sb[1][1] + sb[2][1] + sb[3][1];
  float mu = st * (1.0f / D_);
  float var = qt * (1.0f / D_) - mu * mu;
  float rstd = rsqrtf(var + 1e-6f);
  const float* mb = mod + (size_t)b * 6144 + 3072;
  float4 gm = *(const float4*)(mb + c);
  float4 bt = *(const float4*)(mb + 1024 + c);
  bf16x4 pk;
  pk.x = (__bf16)((xv.x - mu) * rstd * (1.0f + bt.x) + gm.x);
  pk.y = (__bf16)((xv.y - mu) * rstd * (1.0f + bt.y) + gm.y);
  pk.z = (__bf16)((xv.z - mu) * rstd * (1.0f + bt.z) + gm.z);
  pk.w = (__bf16)((xv.w - mu) * rstd * (1.0f + bt.w) + gm.w);
  *(bf16x4*)(h + idx) = pk;
}

// ---------------- W2 split-K(2) reduction + epilogue ----------------
__global__ __launch_bounds__(256) void reduce_w2(
    const float* __restrict__ part, const float* __restrict__ x1,
    const float* __restrict__ b2, const float* __restrict__ mod,
    float* __restrict__ out) {
  const int idx = (blockIdx.x * 256 + threadIdx.x) * 4;
  const int col = idx & 1023;
  const int row = idx >> 10;
  const int b = row >> 10;
  float4 s0 = *(const float4*)(part + idx);
  float4 s1 = *(const float4*)(part + 4194304 + idx);
  float4 bb = *(const float4*)(b2 + col);
  float4 al = *(const float4*)(mod + (size_t)b * 6144 + 5120 + col);
  float4 rs = *(const float4*)(x1 + idx);
  float4 o;
  o.x = rs.x + al.x * (s0.x + s1.x + bb.x);
  o.y = rs.y + al.y * (s0.y + s1.y + bb.y);
  o.z = rs.z + al.z * (s0.z + s1.z + bb.z);
  o.w = rs.w + al.w * (s0.w + s1.w + bb.w);
  *(float4*)(out + idx) = o;
}

extern "C" void kernel_launch(void* const* d_in, const int* in_sizes, int n_in,
                              void* d_out, int out_size, void* d_ws, size_t ws_size,
                              hipStream_t stream) {
  (void)in_sizes; (void)n_in; (void)out_size; (void)ws_size;
  const float* x    = (const float*)d_in[0];
  const float* cond = (const float*)d_in[1];
  const float* Wq   = (const float*)d_in[2];
  const float* bq   = (const float*)d_in[3];
  const float* Wk   = (const float*)d_in[4];
  const float* bk   = (const float*)d_in[5];
  const float* Wv   = (const float*)d_in[6];
  const float* bv   = (const float*)d_in[7];
  const float* Wo   = (const float*)d_in[8];
  const float* bo   = (const float*)d_in[9];
  const float* W1   = (const float*)d_in[10];
  const float* b1   = (const float*)d_in[11];
  const float* W2   = (const float*)d_in[12];
  const float* b2   = (const float*)d_in[13];
  const float* Wada = (const float*)d_in[14];
  const float* bada = (const float*)d_in[15];

  uint8_t* ws = (uint8_t*)d_ws;
  bf16_t* wbf   = (bf16_t*)(ws + OFF_WBF);
  float*  bqkv  = (float*)(ws + OFF_BQKV);
  float*  mod   = (float*)(ws + OFF_MOD);
  bf16_t* h     = (bf16_t*)(ws + OFF_H);
  bf16_t* qkv   = (bf16_t*)(ws + OFF_QKV);
  bf16_t* vT    = (bf16_t*)(ws + OFF_VT);
  bf16_t* attn  = (bf16_t*)(ws + OFF_ATTN);
  float*  x1    = (float*)(ws + OFF_X1);
  float*  part  = (float*)(ws + OFF_PART);
  bf16_t* mlph  = (bf16_t*)(ws + OFF_MLPH);
  float* out = (float*)d_out;

  convert_pack<<<dim3(4096, 7, 1), 256, 0, stream>>>(Wq, Wk, Wv, Wo, W1, W2,
                                                     bq, bk, bv, wbf, bqkv);
  ada_mod<<<1536, 256, 0, stream>>>(cond, Wada, bada, mod);
  ln_modulate<<<4096, 256, 0, stream>>>(x, mod, h, 0);
  // qkv = h @ [Wq;Wk;Wv]^T + bias
  gemm_bt<0><<<dim3(24, 32, 1), 256, 0, stream>>>(
      h, 1024, 0, wbf, 1024, 0, qkv, 3072, 0, 4096, 3072, 1024,
      bqkv, 1.f);
  transpose_v<<<dim3(16, 64, 1), 256, 0, stream>>>(qkv, vT);
  flash_attn<<<dim3(16, 64, 1), 256, 0, stream>>>(qkv, vT, attn);

  // Wo split-K=2: part[z] = attn[:, z*512:] @ Wo[:, z*512:]^T
  gemm_bt<1><<<dim3(8, 32, 2), 256, 0, stream>>>(
      attn, 1024, 512, wbf + (size_t)3 * MEG, 1024, 512, part, 1024, 4194304,
      4096, 1024, 512, nullptr, 1.f);
  // x1 = x + alpha1*(sum part + bo); h = modulate(ln(x1), beta2, gama2)
  reduce_ln<<<4096, 256, 0, stream>>>(part, x, bo, mod, x1, h);

  // mlph = gelu(h @ W1^T + b1)
  gemm_bt<3><<<dim3(32, 32, 1), 256, 0, stream>>>(
      h, 1024, 0, wbf + (size_t)4 * MEG, 1024, 0, mlph, 4096, 0,
      4096, 4096, 1024, b1, 1.f);
  // W2 split-K=2
  gemm_bt<1><<<dim3(8, 32, 2), 256, 0, stream>>>(
      mlph, 4096, 2048, wbf + (size_t)8 * MEG, 4096, 2048, part, 1024, 4194304,
      4096, 1024, 2048, nullptr, 1.f);
  reduce_w2<<<4096, 256, 0, stream>>>(part, x1, b2, mod, out);
}